// Round 4
// baseline (3274.548 us; speedup 1.0000x reference)
//
#include <hip/hip_runtime.h>
#include <hip/hip_bf16.h>

#define H 64
#define PADW 88    // old-path bf16 plane stride (shorts)
#define PADU 136   // old-path bf16 plane stride K=128 (shorts)
#define PADT 68    // old-path f32 transpose-buffer stride (floats)

typedef __attribute__((ext_vector_type(8))) short short8;
typedef __attribute__((ext_vector_type(4))) float floatx4;

#define MFMA(a, b, c) __builtin_amdgcn_mfma_f32_16x16x32_bf16(a, b, c, 0, 0, 0)

__device__ __forceinline__ float bf2f(short s) {
  union { unsigned int u; float f; } v;
  v.u = ((unsigned int)(unsigned short)s) << 16;
  return v.f;
}
__device__ __forceinline__ short f2bf(float f) {
  union { float f; unsigned int u; } v; v.f = f;
  unsigned int r = v.u + 0x7fffu + ((v.u >> 16) & 1u);  // RNE
  return (short)(r >> 16);
}
__device__ __forceinline__ void split2(float v, short& hi, short& lo) {
  hi = f2bf(v);
  lo = f2bf(v - bf2f(hi));
}
// element idx of a float tensor that is either f32 or bf16
__device__ __forceinline__ float ldf(const void* p, long idx, bool isf32) {
  return isf32 ? ((const float*)p)[idx] : bf2f(((const short*)p)[idx]);
}

// dtype probe (kept: harness dtype established as f32, but stay robust)
__global__ void k_probe(const short* __restrict__ x, int* __restrict__ flag) {
  __shared__ int cnt;
  if (threadIdx.x == 0) cnt = 0;
  __syncthreads();
  short s = x[threadIdx.x];
  int e = (s >> 7) & 0xFF;
  int insane = (e != 0 && (e < 100 || e > 140)) ? 1 : 0;
  atomicAdd(&cnt, insane);
  __syncthreads();
  if (threadIdx.x == 0) *flag = (cnt > 64) ? 1 : 0;  // 1 = f32 inputs
}

// h0 = relu(x @ w_in + b_in) -> f32
__global__ void k_input(const void* __restrict__ x, const void* __restrict__ w,
                        const void* __restrict__ b, float* __restrict__ h,
                        const int* __restrict__ flag, int N) {
  bool isf32 = (*flag != 0);
  int idx = blockIdx.x * 256 + threadIdx.x;
  if (idx >= N * H) return;
  int v = idx >> 6, k = idx & 63;
  float acc = ldf(b, k, isf32);
#pragma unroll
  for (int d = 0; d < 3; ++d)
    acc += ldf(x, (long)v * 3 + d, isf32) * ldf(w, d * 64 + k, isf32);
  h[idx] = fmaxf(acc, 0.f);
}

// ---------------- CSR build (counting sort by dst) ----------------

__global__ void k_hist(const int* __restrict__ dstI, int* __restrict__ deg, int E) {
  int e = blockIdx.x * 256 + threadIdx.x;
  if (e < E) atomicAdd(&deg[dstI[e]], 1);
}

// per-block scan of 1024 elements (256 thr x 4); writes local-exclusive into rowptr,
// block total into bsum
__global__ void k_scan_local(const int* __restrict__ deg, int* __restrict__ rowptr,
                             int* __restrict__ bsum, int N) {
  __shared__ int s[256];
  int tid = threadIdx.x;
  int base = blockIdx.x * 1024 + tid * 4;
  int v0 = (base + 0 < N) ? deg[base + 0] : 0;
  int v1 = (base + 1 < N) ? deg[base + 1] : 0;
  int v2 = (base + 2 < N) ? deg[base + 2] : 0;
  int v3 = (base + 3 < N) ? deg[base + 3] : 0;
  int tsum = v0 + v1 + v2 + v3;
  s[tid] = tsum;
  __syncthreads();
  for (int off = 1; off < 256; off <<= 1) {
    int x = (tid >= off) ? s[tid - off] : 0;
    __syncthreads();
    s[tid] += x;
    __syncthreads();
  }
  int excl = s[tid] - tsum;
  if (base + 0 < N) rowptr[base + 0] = excl;
  if (base + 1 < N) rowptr[base + 1] = excl + v0;
  if (base + 2 < N) rowptr[base + 2] = excl + v0 + v1;
  if (base + 3 < N) rowptr[base + 3] = excl + v0 + v1 + v2;
  if (tid == 255) bsum[blockIdx.x] = s[255];
}

// single block scans bsum[nb] -> bexcl (exclusive). requires nb <= 256.
__global__ void k_scan_block(const int* __restrict__ bsum, int* __restrict__ bexcl, int nb) {
  __shared__ int s[256];
  int tid = threadIdx.x;
  int v = (tid < nb) ? bsum[tid] : 0;
  s[tid] = v;
  __syncthreads();
  for (int off = 1; off < 256; off <<= 1) {
    int x = (tid >= off) ? s[tid - off] : 0;
    __syncthreads();
    s[tid] += x;
    __syncthreads();
  }
  bexcl[tid] = s[tid] - v;
}

// rowptr[i] += bexcl[i>>10]; cursor[i] = rowptr[i]; rowptr[N] = E
__global__ void k_scan_add(int* __restrict__ rowptr, int* __restrict__ cursor,
                           const int* __restrict__ bexcl, int N, int E) {
  int i = blockIdx.x * 256 + threadIdx.x;
  if (i < N) {
    int v = rowptr[i] + bexcl[i >> 10];
    rowptr[i] = v;
    cursor[i] = v;
  }
  if (i == N) rowptr[N] = E;
}

__global__ void k_scatter(const int* __restrict__ srcI, const int* __restrict__ dstI,
                          int* __restrict__ cursor, int* __restrict__ srcS, int E) {
  int e = blockIdx.x * 256 + threadIdx.x;
  if (e >= E) return;
  int d = dstI[e];
  int p = atomicAdd(&cursor[d], 1);
  srcS[p] = srcI[e];
}

// ---------------- node-parallel message kernel (no atomics) ----------------
// One wave per dst node; CSR segment processed in 16-edge MFMA chunks.
// GEMM1 transposed (A=W1^T frag-major, B=h gather); P relayout via ds_bpermute;
// GEMM2 normal; per-node row-sum in registers; one coalesced agg-row store.
__global__ __launch_bounds__(256) void k_msg_nodes(
    const float* __restrict__ h, const int* __restrict__ rowptr, const int* __restrict__ srcS,
    const void* __restrict__ W1, const void* __restrict__ B1,
    const void* __restrict__ W2, const void* __restrict__ B2,
    long oW, long oB, float* __restrict__ agg, const int* __restrict__ flag, int N) {
  // fragment-major weight planes: frag_idx(((t*2+c)*64 + lane)*8 + j) -> lane-ordered
  // 16B chunks, conflict-free wave reads, zero padding. 8KB per plane.
  __shared__ short w1hi[4096], w1lo[4096], w2hi[4096], w2lo[4096];
  __shared__ float b1s[64], b2s[64];

  bool isf32 = (*flag != 0);
  int tid = threadIdx.x;
  for (int idx = tid; idx < 4096; idx += 256) {
    int k = idx >> 6, n = idx & 63;  // W[k=in][n=out], row-major (H,H)
    int t = n >> 4, m = n & 15, c = k >> 5, q = (k >> 3) & 3, j = k & 7;
    int fi = (((t * 2 + c) * 64) + (q * 16 + m)) * 8 + j;
    short hi, lo;
    split2(ldf(W1, oW + idx, isf32), hi, lo);
    w1hi[fi] = hi; w1lo[fi] = lo;
    split2(ldf(W2, oW + idx, isf32), hi, lo);
    w2hi[fi] = hi; w2lo[fi] = lo;
  }
  if (tid < 64) { b1s[tid] = ldf(B1, oB + tid, isf32); b2s[tid] = ldf(B2, oB + tid, isf32); }
  __syncthreads();

  const int wave = tid >> 6, lane = tid & 63;
  const int m = lane & 15, q = lane >> 4;
  int n = blockIdx.x * 4 + wave;
  if (n >= N) return;
  int rs = rowptr[n], re = rowptr[n + 1];
  int d = re - rs;

  float b1v[4][4];
#pragma unroll
  for (int t = 0; t < 4; ++t)
#pragma unroll
    for (int r = 0; r < 4; ++r) b1v[t][r] = b1s[16 * t + 4 * q + r];

  floatx4 sum[4];
#pragma unroll
  for (int t = 0; t < 4; ++t) sum[t] = (floatx4){0.f, 0.f, 0.f, 0.f};

  for (int base = rs; base < re; base += 16) {
    int e = base + m;
    int ec = e < re ? e : re - 1;
    int sv = srcS[ec];
    const float* hrow = h + (long)sv * H;
    // B-fragment of h: lane(m,q) holds h[src_m][32c + 8q + j]
    float av[16];
    *(floatx4*)(av + 0)  = *(const floatx4*)(hrow + 8 * q);
    *(floatx4*)(av + 4)  = *(const floatx4*)(hrow + 8 * q + 4);
    *(floatx4*)(av + 8)  = *(const floatx4*)(hrow + 32 + 8 * q);
    *(floatx4*)(av + 12) = *(const floatx4*)(hrow + 32 + 8 * q + 4);
    short8 bhi0, blo0, bhi1, blo1;
#pragma unroll
    for (int j = 0; j < 8; ++j) {
      short hi, lo;
      split2(av[j], hi, lo);     bhi0[j] = hi; blo0[j] = lo;
      split2(av[8 + j], hi, lo); bhi1[j] = hi; blo1[j] = lo;
    }

    // GEMM1': P^T = W1^T @ h^T. Output lane(m,q) reg r tile t = P[e=m][f=16t+4q+r]
    floatx4 p4[4];
#pragma unroll
    for (int t = 0; t < 4; ++t) p4[t] = (floatx4){0.f, 0.f, 0.f, 0.f};
#pragma unroll
    for (int t = 0; t < 4; ++t) {
      const short8 a0h = *(const short8*)&w1hi[(((t * 2 + 0) * 64) + lane) * 8];
      const short8 a0l = *(const short8*)&w1lo[(((t * 2 + 0) * 64) + lane) * 8];
      const short8 a1h = *(const short8*)&w1hi[(((t * 2 + 1) * 64) + lane) * 8];
      const short8 a1l = *(const short8*)&w1lo[(((t * 2 + 1) * 64) + lane) * 8];
      p4[t] = MFMA(a0h, bhi0, p4[t]);
      p4[t] = MFMA(a0l, bhi0, p4[t]);
      p4[t] = MFMA(a0h, blo0, p4[t]);
      p4[t] = MFMA(a1h, bhi1, p4[t]);
      p4[t] = MFMA(a1l, bhi1, p4[t]);
      p4[t] = MFMA(a1h, blo1, p4[t]);
    }
    float pv[4][4];
#pragma unroll
    for (int t = 0; t < 4; ++t)
#pragma unroll
      for (int r = 0; r < 4; ++r) pv[t][r] = fmaxf(p4[t][r] + b1v[t][r], 0.f);

    // relayout P to GEMM2 A-fragment via shuffles:
    // target lane(m,q) needs P[e=m][f=32c+8q+j] held by lane (qs<<4)|m,
    // qs=(2q+(j>>2))&3, reg pv[2c+(q>>1)][j&3]. Verified: 16t_s+4qs+r_s == 32c+8q+j.
    short8 ahi[2], alo[2];
#pragma unroll
    for (int c = 0; c < 2; ++c) {
#pragma unroll
      for (int j = 0; j < 8; ++j) {
        int qs = (2 * q + (j >> 2)) & 3;
        int L = (qs << 4) | m;
        float v0 = __shfl(pv[2 * c + 0][j & 3], L);
        float v1 = __shfl(pv[2 * c + 1][j & 3], L);
        float val = (q & 2) ? v1 : v0;
        short hi, lo;
        split2(val, hi, lo);
        ahi[c][j] = hi; alo[c][j] = lo;
      }
    }

    // GEMM2: M = P @ W2. Output lane(m,q) reg r tile t = M[e=4q+r][col=16t+m]
    floatx4 m4[4];
#pragma unroll
    for (int t = 0; t < 4; ++t) m4[t] = (floatx4){0.f, 0.f, 0.f, 0.f};
#pragma unroll
    for (int t = 0; t < 4; ++t) {
      const short8 b0h = *(const short8*)&w2hi[(((t * 2 + 0) * 64) + lane) * 8];
      const short8 b0l = *(const short8*)&w2lo[(((t * 2 + 0) * 64) + lane) * 8];
      const short8 b1h = *(const short8*)&w2hi[(((t * 2 + 1) * 64) + lane) * 8];
      const short8 b1l = *(const short8*)&w2lo[(((t * 2 + 1) * 64) + lane) * 8];
      m4[t] = MFMA(ahi[0], b0h, m4[t]);
      m4[t] = MFMA(alo[0], b0h, m4[t]);
      m4[t] = MFMA(ahi[0], b0l, m4[t]);
      m4[t] = MFMA(ahi[1], b1h, m4[t]);
      m4[t] = MFMA(alo[1], b1h, m4[t]);
      m4[t] = MFMA(ahi[1], b1l, m4[t]);
    }

    // masked accumulate (invalid tail rows contribute nothing; bias handled as d*b2)
#pragma unroll
    for (int t = 0; t < 4; ++t)
#pragma unroll
      for (int r = 0; r < 4; ++r)
        if (base + 4 * q + r < re) sum[t][r] += m4[t][r];
  }

  // reduce row-partials across quads; lane l writes col l = 16q+m
  float red[4];
#pragma unroll
  for (int t = 0; t < 4; ++t) {
    float s = sum[t][0] + sum[t][1] + sum[t][2] + sum[t][3];
    s += __shfl_xor(s, 16);
    s += __shfl_xor(s, 32);
    red[t] = s;
  }
  float v01 = (q & 1) ? red[1] : red[0];
  float v23 = (q & 1) ? red[3] : red[2];
  float v = (q & 2) ? v23 : v01;
  v += (float)d * b2s[lane];
  agg[(long)n * H + lane] = v;
}

// ---------------- old-path edge-parallel message kernel (fallback) ----------------
template <bool AF32>
__global__ __launch_bounds__(256) void k_msg(
    const float* __restrict__ h, const int* __restrict__ srcI, const int* __restrict__ dstI,
    const void* __restrict__ W1, const void* __restrict__ B1,
    const void* __restrict__ W2, const void* __restrict__ B2,
    long oW, long oB,
    void* __restrict__ aggv, const int* __restrict__ flag, int E) {
  __shared__ short w1hi[64 * PADW], w1lo[64 * PADW];
  __shared__ short w2hi[64 * PADW], w2lo[64 * PADW];
  __shared__ float b1s[64], b2s[64];
  __shared__ float tbuf[4][16 * PADT];

  bool isf32 = (*flag != 0);
  int tid = threadIdx.x;
  for (int idx = tid; idx < 4096; idx += 256) {
    int j = idx >> 6, k = idx & 63;
    short hi, lo;
    split2(ldf(W1, oW + idx, isf32), hi, lo);
    w1hi[k * PADW + j] = hi; w1lo[k * PADW + j] = lo;
    split2(ldf(W2, oW + idx, isf32), hi, lo);
    w2hi[k * PADW + j] = hi; w2lo[k * PADW + j] = lo;
  }
  if (tid < 64) {
    b1s[tid] = ldf(B1, oB + tid, isf32);
    b2s[tid] = ldf(B2, oB + tid, isf32);
  }
  __syncthreads();

  const int wave = tid >> 6, lane = tid & 63;
  const int m = lane & 15, quad = lane >> 4;
  const int eBase = (blockIdx.x * 4 + wave) * 16;

  int e = eBase + m;
  int ec = e < E ? e : E - 1;
  int sv = srcI[ec];
  int dv = dstI[ec];

  const float* hrow = h + (long)sv * H;
  float av[16];
  *(floatx4*)(av + 0)  = *(const floatx4*)(hrow + quad * 8);
  *(floatx4*)(av + 4)  = *(const floatx4*)(hrow + quad * 8 + 4);
  *(floatx4*)(av + 8)  = *(const floatx4*)(hrow + 32 + quad * 8);
  *(floatx4*)(av + 12) = *(const floatx4*)(hrow + 32 + quad * 8 + 4);
  short8 ahi0, alo0, ahi1, alo1;
#pragma unroll
  for (int j = 0; j < 8; ++j) {
    short hi, lo;
    split2(av[j], hi, lo);     ahi0[j] = hi; alo0[j] = lo;
    split2(av[8 + j], hi, lo); ahi1[j] = hi; alo1[j] = lo;
  }

  floatx4 acc[4];
#pragma unroll
  for (int t = 0; t < 4; ++t) acc[t] = (floatx4){0.f, 0.f, 0.f, 0.f};
#pragma unroll
  for (int t = 0; t < 4; ++t) {
    const short* whi = &w1hi[(t * 16 + m) * PADW + quad * 8];
    const short* wlo = &w1lo[(t * 16 + m) * PADW + quad * 8];
    acc[t] = MFMA(ahi0, *(const short8*)(whi), acc[t]);
    acc[t] = MFMA(ahi1, *(const short8*)(whi + 32), acc[t]);
    acc[t] = MFMA(alo0, *(const short8*)(whi), acc[t]);
    acc[t] = MFMA(alo1, *(const short8*)(whi + 32), acc[t]);
    acc[t] = MFMA(ahi0, *(const short8*)(wlo), acc[t]);
    acc[t] = MFMA(ahi1, *(const short8*)(wlo + 32), acc[t]);
  }

  float* tb = tbuf[wave];
#pragma unroll
  for (int t = 0; t < 4; ++t) {
    int col = t * 16 + m;
    float bb = b1s[col];
#pragma unroll
    for (int r = 0; r < 4; ++r)
      tb[(quad * 4 + r) * PADT + col] = fmaxf(acc[t][r] + bb, 0.f);
  }
  __syncthreads();

  *(floatx4*)(av + 0)  = *(const floatx4*)(&tb[m * PADT + quad * 8]);
  *(floatx4*)(av + 4)  = *(const floatx4*)(&tb[m * PADT + quad * 8 + 4]);
  *(floatx4*)(av + 8)  = *(const floatx4*)(&tb[m * PADT + 32 + quad * 8]);
  *(floatx4*)(av + 12) = *(const floatx4*)(&tb[m * PADT + 32 + quad * 8 + 4]);
#pragma unroll
  for (int j = 0; j < 8; ++j) {
    short hi, lo;
    split2(av[j], hi, lo);     ahi0[j] = hi; alo0[j] = lo;
    split2(av[8 + j], hi, lo); ahi1[j] = hi; alo1[j] = lo;
  }

  floatx4 mac[4];
#pragma unroll
  for (int t = 0; t < 4; ++t) mac[t] = (floatx4){0.f, 0.f, 0.f, 0.f};
#pragma unroll
  for (int t = 0; t < 4; ++t) {
    const short* whi = &w2hi[(t * 16 + m) * PADW + quad * 8];
    const short* wlo = &w2lo[(t * 16 + m) * PADW + quad * 8];
    mac[t] = MFMA(ahi0, *(const short8*)(whi), mac[t]);
    mac[t] = MFMA(ahi1, *(const short8*)(whi + 32), mac[t]);
    mac[t] = MFMA(alo0, *(const short8*)(whi), mac[t]);
    mac[t] = MFMA(alo1, *(const short8*)(whi + 32), mac[t]);
    mac[t] = MFMA(ahi0, *(const short8*)(wlo), mac[t]);
    mac[t] = MFMA(ahi1, *(const short8*)(wlo + 32), mac[t]);
  }

  float* aggF = (float*)aggv;
  short* aggS = (short*)aggv;
#pragma unroll
  for (int t = 0; t < 4; ++t) {
    int col = t * 16 + m;
    float bb = b2s[col];
#pragma unroll
    for (int r = 0; r < 4; ++r) {
      int row = quad * 4 + r;
      int er = eBase + row;
      int dr = __shfl(dv, row);
      float v = mac[t][r] + bb;
      if (AF32) {
        if (er < E) atomicAdd(&aggF[(long)dr * H + col], v);
      } else {
        float v2 = __shfl_down(v, 1);
        if (((m & 1) == 0) && er < E) {
          unsigned int pk = ((unsigned int)(unsigned short)f2bf(v2) << 16) |
                            (unsigned int)(unsigned short)f2bf(v);
          unsafeAtomicAdd((__hip_bfloat162*)&aggS[(long)dr * H + col],
                          *(__hip_bfloat162*)&pk);
        }
      }
    }
  }
}

// per-node update MLP + BN + residual relu (split-bf16 MFMA). In-place safe.
template <bool AF32>
__global__ __launch_bounds__(256) void k_upd(
    const float* __restrict__ h, const void* __restrict__ aggv,
    const void* __restrict__ W1, const void* __restrict__ B1,
    const void* __restrict__ W2, const void* __restrict__ B2,
    const void* __restrict__ G, const void* __restrict__ Bb,
    const void* __restrict__ Mm, const void* __restrict__ Vv,
    long oU, long oW, long oB,
    float* __restrict__ hout, const int* __restrict__ flag, int N) {
  __shared__ short w1hi[64 * PADU], w1lo[64 * PADU];
  __shared__ short w2hi[64 * PADW], w2lo[64 * PADW];
  __shared__ float b1s[64], b2s[64], scl[64], sft[64];
  __shared__ float tbuf[4][16 * PADT];

  bool isf32 = (*flag != 0);
  int tid = threadIdx.x;
  for (int idx = tid; idx < 8192; idx += 256) {
    int j = idx >> 6, k = idx & 63;
    short hi, lo;
    split2(ldf(W1, oU + idx, isf32), hi, lo);
    w1hi[k * PADU + j] = hi; w1lo[k * PADU + j] = lo;
  }
  for (int idx = tid; idx < 4096; idx += 256) {
    int j = idx >> 6, k = idx & 63;
    short hi, lo;
    split2(ldf(W2, oW + idx, isf32), hi, lo);
    w2hi[k * PADW + j] = hi; w2lo[k * PADW + j] = lo;
  }
  if (tid < 64) {
    b1s[tid] = ldf(B1, oB + tid, isf32);
    b2s[tid] = ldf(B2, oB + tid, isf32);
    float s = ldf(G, oB + tid, isf32) * rsqrtf(ldf(Vv, oB + tid, isf32) + 1e-5f);
    scl[tid] = s;
    sft[tid] = ldf(Bb, oB + tid, isf32) - ldf(Mm, oB + tid, isf32) * s;
  }
  __syncthreads();

  const int wave = tid >> 6, lane = tid & 63;
  const int m = lane & 15, quad = lane >> 4;
  const int nBase = (blockIdx.x * 4 + wave) * 16;
  int node = nBase + m;
  int nc = node < N ? node : N - 1;

  float av[16];
  const float* hrow = h + (long)nc * H;
  *(floatx4*)(av + 0)  = *(const floatx4*)(hrow + quad * 8);
  *(floatx4*)(av + 4)  = *(const floatx4*)(hrow + quad * 8 + 4);
  *(floatx4*)(av + 8)  = *(const floatx4*)(hrow + 32 + quad * 8);
  *(floatx4*)(av + 12) = *(const floatx4*)(hrow + 32 + quad * 8 + 4);
  float gv[16];
  if (AF32) {
    const float* arow = (const float*)aggv + (long)nc * H;
    *(floatx4*)(gv + 0)  = *(const floatx4*)(arow + quad * 8);
    *(floatx4*)(gv + 4)  = *(const floatx4*)(arow + quad * 8 + 4);
    *(floatx4*)(gv + 8)  = *(const floatx4*)(arow + 32 + quad * 8);
    *(floatx4*)(gv + 12) = *(const floatx4*)(arow + 32 + quad * 8 + 4);
  } else {
    const short* arow = (const short*)aggv + (long)nc * H;
#pragma unroll
    for (int j = 0; j < 8; ++j) {
      gv[j] = bf2f(arow[quad * 8 + j]);
      gv[8 + j] = bf2f(arow[32 + quad * 8 + j]);
    }
  }
  short8 fhi[4], flo[4];
#pragma unroll
  for (int j = 0; j < 8; ++j) {
    short hi, lo;
    split2(av[j], hi, lo);      fhi[0][j] = hi; flo[0][j] = lo;
    split2(av[8 + j], hi, lo);  fhi[1][j] = hi; flo[1][j] = lo;
    split2(gv[j], hi, lo);      fhi[2][j] = hi; flo[2][j] = lo;
    split2(gv[8 + j], hi, lo);  fhi[3][j] = hi; flo[3][j] = lo;
  }

  floatx4 acc[4];
#pragma unroll
  for (int t = 0; t < 4; ++t) acc[t] = (floatx4){0.f, 0.f, 0.f, 0.f};
#pragma unroll
  for (int t = 0; t < 4; ++t) {
    const short* whi = &w1hi[(t * 16 + m) * PADU + quad * 8];
    const short* wlo = &w1lo[(t * 16 + m) * PADU + quad * 8];
#pragma unroll
    for (int c = 0; c < 4; ++c) {
      acc[t] = MFMA(fhi[c], *(const short8*)(whi + 32 * c), acc[t]);
      acc[t] = MFMA(flo[c], *(const short8*)(whi + 32 * c), acc[t]);
      acc[t] = MFMA(fhi[c], *(const short8*)(wlo + 32 * c), acc[t]);
    }
  }

  float* tb = tbuf[wave];
#pragma unroll
  for (int t = 0; t < 4; ++t) {
    int col = t * 16 + m;
    float bb = b1s[col];
#pragma unroll
    for (int r = 0; r < 4; ++r)
      tb[(quad * 4 + r) * PADT + col] = fmaxf(acc[t][r] + bb, 0.f);
  }
  __syncthreads();

  *(floatx4*)(av + 0)  = *(const floatx4*)(&tb[m * PADT + quad * 8]);
  *(floatx4*)(av + 4)  = *(const floatx4*)(&tb[m * PADT + quad * 8 + 4]);
  *(floatx4*)(av + 8)  = *(const floatx4*)(&tb[m * PADT + 32 + quad * 8]);
  *(floatx4*)(av + 12) = *(const floatx4*)(&tb[m * PADT + 32 + quad * 8 + 4]);
  short8 thi0, tlo0, thi1, tlo1;
#pragma unroll
  for (int j = 0; j < 8; ++j) {
    short hi, lo;
    split2(av[j], hi, lo);     thi0[j] = hi; tlo0[j] = lo;
    split2(av[8 + j], hi, lo); thi1[j] = hi; tlo1[j] = lo;
  }

  floatx4 mac[4];
#pragma unroll
  for (int t = 0; t < 4; ++t) mac[t] = (floatx4){0.f, 0.f, 0.f, 0.f};
#pragma unroll
  for (int t = 0; t < 4; ++t) {
    const short* whi = &w2hi[(t * 16 + m) * PADW + quad * 8];
    const short* wlo = &w2lo[(t * 16 + m) * PADW + quad * 8];
    mac[t] = MFMA(thi0, *(const short8*)(whi), mac[t]);
    mac[t] = MFMA(thi1, *(const short8*)(whi + 32), mac[t]);
    mac[t] = MFMA(tlo0, *(const short8*)(whi), mac[t]);
    mac[t] = MFMA(tlo1, *(const short8*)(whi + 32), mac[t]);
    mac[t] = MFMA(thi0, *(const short8*)(wlo), mac[t]);
    mac[t] = MFMA(thi1, *(const short8*)(wlo + 32), mac[t]);
  }

#pragma unroll
  for (int t = 0; t < 4; ++t) {
    int col = t * 16 + m;
    float bb = b2s[col], ss = scl[col], ff = sft[col];
#pragma unroll
    for (int r = 0; r < 4; ++r) {
      int nrow = nBase + quad * 4 + r;
      if (nrow < N) {
        float hv = (mac[t][r] + bb) * ss + ff;
        float ho = h[(long)nrow * H + col];
        hout[(long)nrow * H + col] = fmaxf(hv + ho, 0.f);
      }
    }
  }
}

// out = relu(h[:NQ] @ out_w1 + b1) @ out_w2 + b2
__global__ __launch_bounds__(256) void k_out(
    const float* __restrict__ h, const void* __restrict__ W1, const void* __restrict__ B1,
    const void* __restrict__ W2, const void* __restrict__ B2,
    void* __restrict__ out, const int* __restrict__ flag, int NQ) {
  __shared__ float w1s[64 * 32];
  __shared__ float b1sh[32], w2s[32];
  bool isf32 = (*flag != 0);
  int tid = threadIdx.x;
  for (int idx = tid; idx < 2048; idx += 256) w1s[idx] = ldf(W1, idx, isf32);
  if (tid < 32) { b1sh[tid] = ldf(B1, tid, isf32); w2s[tid] = ldf(W2, tid, isf32); }
  __syncthreads();
  int v = blockIdx.x * 256 + tid;
  if (v >= NQ) return;
  float hr[64];
  const float* hp = h + (long)v * H;
#pragma unroll
  for (int j = 0; j < 64; ++j) hr[j] = hp[j];
  float accum = ldf(B2, 0, isf32);
#pragma unroll 4
  for (int k = 0; k < 32; ++k) {
    float t = b1sh[k];
#pragma unroll
    for (int j = 0; j < 64; ++j) t += hr[j] * w1s[j * 32 + k];
    accum += fmaxf(t, 0.f) * w2s[k];
  }
  if (isf32) ((float*)out)[v] = accum;
  else ((short*)out)[v] = f2bf(accum);
}

extern "C" void kernel_launch(void* const* d_in, const int* in_sizes, int n_in,
                              void* d_out, int out_size, void* d_ws, size_t ws_size,
                              hipStream_t stream) {
  const void* x      = d_in[0];
  const int*  ei     = (const int*)d_in[1];
  const void* w_in   = d_in[3];
  const void* b_in   = d_in[4];
  const void* msg_w1 = d_in[5];
  const void* msg_b1 = d_in[6];
  const void* msg_w2 = d_in[7];
  const void* msg_b2 = d_in[8];
  const void* upd_w1 = d_in[9];
  const void* upd_b1 = d_in[10];
  const void* upd_w2 = d_in[11];
  const void* upd_b2 = d_in[12];
  const void* bn_g   = d_in[13];
  const void* bn_b   = d_in[14];
  const void* bn_m   = d_in[15];
  const void* bn_v   = d_in[16];
  const void* out_w1 = d_in[17];
  const void* out_b1 = d_in[18];
  const void* out_w2 = d_in[19];
  const void* out_b2 = d_in[20];

  const int N = in_sizes[0] / 3;
  const int E = in_sizes[1] / 2;
  const int L = in_sizes[5] / (H * H);
  const int* srcI = ei;
  const int* dstI = ei + E;

  // workspace layout (256B-aligned slots)
  size_t off = 0;
  auto alloc = [&](size_t bytes) { size_t o = off; off += (bytes + 255) & ~(size_t)255; return o; };
  size_t o_flag   = alloc(256);
  size_t o_h      = alloc((size_t)N * H * sizeof(float));
  size_t o_agg    = alloc((size_t)N * H * sizeof(float));
  size_t o_rowptr = alloc((size_t)(N + 1) * sizeof(int));
  size_t o_cursor = alloc((size_t)N * sizeof(int));       // doubles as deg
  size_t o_bsum   = alloc(256 * sizeof(int));
  size_t o_bexcl  = alloc(256 * sizeof(int));
  size_t o_srcS   = alloc((size_t)E * sizeof(int));
  const size_t needNew = off;
  const int NB = (N + 1023) >> 10;
  const bool newPath = (ws_size >= needNew) && (NB <= 256);

  char* ws = (char*)d_ws;
  int*   flag   = (int*)(ws + o_flag);
  float* hA     = (float*)(ws + o_h);
  float* agg    = (float*)(ws + o_agg);
  int*   rowptr = (int*)(ws + o_rowptr);
  int*   deg    = (int*)(ws + o_cursor);  // histogram, then scatter cursor
  int*   bsum   = (int*)(ws + o_bsum);
  int*   bexcl  = (int*)(ws + o_bexcl);
  int*   srcS   = (int*)(ws + o_srcS);

  k_probe<<<1, 256, 0, stream>>>((const short*)x, flag);
  k_input<<<(N * H + 255) / 256, 256, 0, stream>>>(x, w_in, b_in, hA, flag, N);

  if (newPath) {
    // CSR build (edge_index constant across layers: sort once per call)
    hipMemsetAsync(deg, 0, (size_t)N * sizeof(int), stream);
    k_hist<<<(E + 255) / 256, 256, 0, stream>>>(dstI, deg, E);
    k_scan_local<<<NB, 256, 0, stream>>>(deg, rowptr, bsum, N);
    k_scan_block<<<1, 256, 0, stream>>>(bsum, bexcl, NB);
    k_scan_add<<<(N + 256) / 256, 256, 0, stream>>>(rowptr, deg, bexcl, N, E);
    k_scatter<<<(E + 255) / 256, 256, 0, stream>>>(srcI, dstI, deg, srcS, E);

    for (int i = 0; i < L; ++i) {
      long oW = (long)i * H * H, oU = (long)i * 2 * H * H, oB = (long)i * H;
      k_msg_nodes<<<(N + 3) / 4, 256, 0, stream>>>(hA, rowptr, srcS,
          msg_w1, msg_b1, msg_w2, msg_b2, oW, oB, agg, flag, N);
      k_upd<true><<<(N + 63) / 64, 256, 0, stream>>>(hA, agg,
          upd_w1, upd_b1, upd_w2, upd_b2, bn_g, bn_b, bn_m, bn_v,
          oU, oW, oB, hA, flag, N);
    }
  } else {
    // fallback: round-3 atomic path
    const size_t hBytes   = (size_t)N * H * sizeof(float);
    const size_t aggF32B  = (size_t)N * H * sizeof(float);
    const size_t aggBf16B = (size_t)N * H * sizeof(short);
    float* hA2 = (float*)(ws + 256);
    void* agg2 = (void*)((char*)hA2 + hBytes);
    const bool af32 = (ws_size >= 256 + hBytes + aggF32B);
    const size_t aggBytes = af32 ? aggF32B : aggBf16B;
    for (int i = 0; i < L; ++i) {
      long oW = (long)i * H * H, oU = (long)i * 2 * H * H, oB = (long)i * H;
      hipMemsetAsync(agg2, 0, aggBytes, stream);
      if (af32) {
        k_msg<true><<<(E + 63) / 64, 256, 0, stream>>>(hA2, srcI, dstI,
            msg_w1, msg_b1, msg_w2, msg_b2, oW, oB, agg2, flag, E);
        k_upd<true><<<(N + 63) / 64, 256, 0, stream>>>(hA2, agg2,
            upd_w1, upd_b1, upd_w2, upd_b2, bn_g, bn_b, bn_m, bn_v,
            oU, oW, oB, hA2, flag, N);
      } else {
        k_msg<false><<<(E + 63) / 64, 256, 0, stream>>>(hA2, srcI, dstI,
            msg_w1, msg_b1, msg_w2, msg_b2, oW, oB, agg2, flag, E);
        k_upd<false><<<(N + 63) / 64, 256, 0, stream>>>(hA2, agg2,
            upd_w1, upd_b1, upd_w2, upd_b2, bn_g, bn_b, bn_m, bn_v,
            oU, oW, oB, hA2, flag, N);
      }
    }
    hA = hA2;
  }

  k_out<<<(out_size + 255) / 256, 256, 0, stream>>>(hA, out_w1, out_b1, out_w2, out_b2,
                                                    d_out, flag, out_size);
}

// Round 5
// 1494.795 us; speedup vs baseline: 2.1906x; 2.1906x over previous
//
#include <hip/hip_runtime.h>
#include <hip/hip_bf16.h>

#define H 64
#define PADW 88    // old-path bf16 plane stride (shorts)
#define PADU 136   // old-path bf16 plane stride K=128 (shorts)
#define PADT 68    // old-path f32 transpose-buffer stride (floats)
#define BSTR 68    // msg2 batch-buffer row stride (dwords): 16B-aligned, <=2-way banks

typedef __attribute__((ext_vector_type(8))) short short8;
typedef __attribute__((ext_vector_type(4))) float floatx4;
typedef __attribute__((ext_vector_type(4))) unsigned int uintx4;

#define MFMA(a, b, c) __builtin_amdgcn_mfma_f32_16x16x32_bf16(a, b, c, 0, 0, 0)

__device__ __forceinline__ float bf2f(short s) {
  union { unsigned int u; float f; } v;
  v.u = ((unsigned int)(unsigned short)s) << 16;
  return v.f;
}
__device__ __forceinline__ short f2bf(float f) {
  union { float f; unsigned int u; } v; v.f = f;
  unsigned int r = v.u + 0x7fffu + ((v.u >> 16) & 1u);  // RNE
  return (short)(r >> 16);
}
__device__ __forceinline__ void split2(float v, short& hi, short& lo) {
  hi = f2bf(v);
  lo = f2bf(v - bf2f(hi));
}
__device__ __forceinline__ unsigned int packhl(float v) {
  short hi, lo; split2(v, hi, lo);
  return ((unsigned int)(unsigned short)hi << 16) | (unsigned int)(unsigned short)lo;
}
// element idx of a float tensor that is either f32 or bf16
__device__ __forceinline__ float ldf(const void* p, long idx, bool isf32) {
  return isf32 ? ((const float*)p)[idx] : bf2f(((const short*)p)[idx]);
}
// unpack 8 packed (hi<<16|lo) dwords into two bf16 short8 fragments
__device__ __forceinline__ void unpack8(const unsigned int* p, short8& hi, short8& lo) {
  unsigned int u[8];
  *(uintx4*)(u) = *(const uintx4*)(p);
  *(uintx4*)(u + 4) = *(const uintx4*)(p + 4);
#pragma unroll
  for (int j = 0; j < 8; ++j) { hi[j] = (short)(u[j] >> 16); lo[j] = (short)(u[j] & 0xffff); }
}

// dtype probe
__global__ void k_probe(const short* __restrict__ x, int* __restrict__ flag) {
  __shared__ int cnt;
  if (threadIdx.x == 0) cnt = 0;
  __syncthreads();
  short s = x[threadIdx.x];
  int e = (s >> 7) & 0xFF;
  int insane = (e != 0 && (e < 100 || e > 140)) ? 1 : 0;
  atomicAdd(&cnt, insane);
  __syncthreads();
  if (threadIdx.x == 0) *flag = (cnt > 64) ? 1 : 0;  // 1 = f32 inputs
}

// ---------------- new path: h stored as bf16 hi/lo planes ----------------

// h0 = relu(x @ w_in + b_in) -> hi/lo planes
__global__ void k_input2(const void* __restrict__ x, const void* __restrict__ w,
                         const void* __restrict__ b, short* __restrict__ hhi,
                         short* __restrict__ hlo, const int* __restrict__ flag, int N) {
  bool isf32 = (*flag != 0);
  int idx = blockIdx.x * 256 + threadIdx.x;
  if (idx >= N * H) return;
  int v = idx >> 6, k = idx & 63;
  float acc = ldf(b, k, isf32);
#pragma unroll
  for (int d = 0; d < 3; ++d)
    acc += ldf(x, (long)v * 3 + d, isf32) * ldf(w, d * 64 + k, isf32);
  float r = fmaxf(acc, 0.f);
  short hi, lo; split2(r, hi, lo);
  hhi[idx] = hi; hlo[idx] = lo;
}

// ---------------- CSR build (counting sort by dst) ----------------

__global__ void k_hist(const int* __restrict__ dstI, int* __restrict__ deg, int E) {
  int e = blockIdx.x * 256 + threadIdx.x;
  if (e < E) atomicAdd(&deg[dstI[e]], 1);
}

__global__ void k_scan_local(const int* __restrict__ deg, int* __restrict__ rowptr,
                             int* __restrict__ bsum, int N) {
  __shared__ int s[256];
  int tid = threadIdx.x;
  int base = blockIdx.x * 1024 + tid * 4;
  int v0 = (base + 0 < N) ? deg[base + 0] : 0;
  int v1 = (base + 1 < N) ? deg[base + 1] : 0;
  int v2 = (base + 2 < N) ? deg[base + 2] : 0;
  int v3 = (base + 3 < N) ? deg[base + 3] : 0;
  int tsum = v0 + v1 + v2 + v3;
  s[tid] = tsum;
  __syncthreads();
  for (int off = 1; off < 256; off <<= 1) {
    int x = (tid >= off) ? s[tid - off] : 0;
    __syncthreads();
    s[tid] += x;
    __syncthreads();
  }
  int excl = s[tid] - tsum;
  if (base + 0 < N) rowptr[base + 0] = excl;
  if (base + 1 < N) rowptr[base + 1] = excl + v0;
  if (base + 2 < N) rowptr[base + 2] = excl + v0 + v1;
  if (base + 3 < N) rowptr[base + 3] = excl + v0 + v1 + v2;
  if (tid == 255) bsum[blockIdx.x] = s[255];
}

__global__ void k_scan_block(const int* __restrict__ bsum, int* __restrict__ bexcl, int nb) {
  __shared__ int s[256];
  int tid = threadIdx.x;
  int v = (tid < nb) ? bsum[tid] : 0;
  s[tid] = v;
  __syncthreads();
  for (int off = 1; off < 256; off <<= 1) {
    int x = (tid >= off) ? s[tid - off] : 0;
    __syncthreads();
    s[tid] += x;
    __syncthreads();
  }
  bexcl[tid] = s[tid] - v;
}

__global__ void k_scan_add(int* __restrict__ rowptr, int* __restrict__ cursor,
                           const int* __restrict__ bexcl, int N, int E) {
  int i = blockIdx.x * 256 + threadIdx.x;
  if (i < N) {
    int v = rowptr[i] + bexcl[i >> 10];
    rowptr[i] = v;
    cursor[i] = v;
  }
  if (i == N) rowptr[N] = E;
}

__global__ void k_scatter(const int* __restrict__ srcI, const int* __restrict__ dstI,
                          int* __restrict__ cursor, int* __restrict__ srcS, int E) {
  int e = blockIdx.x * 256 + threadIdx.x;
  if (e >= E) return;
  int d = dstI[e];
  int p = atomicAdd(&cursor[d], 1);
  srcS[p] = srcI[e];
}

// ---------------- persistent node-parallel message kernel v2 ----------------
// Grid-stride over 16-node batches. Per chunk: GEMM1 only (round-3-verified
// orientation: A=h[e=m], B=W1 from REGISTERS, P[e=4q+r][f=16t+m]) + relu/mask/acc.
// e-sum: in-lane over r + 2 shfl_xor per node. GEMM2 once per 16-node batch on
// sumP (linear: sum(relu(P)@W2) = sum(relu(P))@W2; bias as deg*b2).
__global__ __launch_bounds__(256) void k_msg2(
    const short* __restrict__ hhi, const short* __restrict__ hlo,
    const int* __restrict__ rowptr, const int* __restrict__ srcS,
    const void* __restrict__ W1, const void* __restrict__ B1,
    const void* __restrict__ W2, const void* __restrict__ B2,
    long oW, long oB, float* __restrict__ agg, const int* __restrict__ flag,
    int N, int totWaves) {
  __shared__ unsigned int w1p[4096];           // packed hi|lo, B-frag fragment-major
  __shared__ unsigned int w2p[4096];
  __shared__ unsigned int batch[4][16 * BSTR]; // per-wave sumP rows (packed hi|lo)
  __shared__ int degs[4][16];
  __shared__ float b1s[64], b2s[64];

  bool isf32 = (*flag != 0);
  int tid = threadIdx.x;
  for (int idx = tid; idx < 4096; idx += 256) {
    int k = idx >> 6, n = idx & 63;  // W[k=in][n=out] row-major
    int t = n >> 4, m = n & 15, c = k >> 5, q = (k >> 3) & 3, j = k & 7;
    int fi = (((t * 2 + c) * 64) + (q * 16 + m)) * 8 + j;
    w1p[fi] = packhl(ldf(W1, oW + idx, isf32));
    w2p[fi] = packhl(ldf(W2, oW + idx, isf32));
  }
  if (tid < 64) { b1s[tid] = ldf(B1, oB + tid, isf32); b2s[tid] = ldf(B2, oB + tid, isf32); }
  __syncthreads();

  const int wave = tid >> 6, lane = tid & 63;
  const int m = lane & 15, q = lane >> 4;

  // hoist W1 fragments into registers (reused every chunk)
  short8 w1hiR[4][2], w1loR[4][2];
#pragma unroll
  for (int t = 0; t < 4; ++t)
#pragma unroll
    for (int c = 0; c < 2; ++c)
      unpack8(&w1p[(((t * 2 + c) * 64) + lane) * 8], w1hiR[t][c], w1loR[t][c]);
  float b1r[4];
#pragma unroll
  for (int t = 0; t < 4; ++t) b1r[t] = b1s[16 * t + m];

  const int gw = blockIdx.x * 4 + wave;
  const int nBatch = (N + 15) >> 4;
  unsigned int* bb_buf = batch[wave];

  for (int bb = gw; bb < nBatch; bb += totWaves) {
    const int nb0 = bb * 16;
    // ---- per-node chunk loops ----
    for (int b = 0; b < 16; ++b) {
      int node = nb0 + b;
      int rs = 0, re = 0;
      if (node < N) { rs = rowptr[node]; re = rowptr[node + 1]; }
      floatx4 sum[4];
#pragma unroll
      for (int t = 0; t < 4; ++t) sum[t] = (floatx4){0.f, 0.f, 0.f, 0.f};

      for (int base = rs; base < re; base += 16) {
        int e = base + m;
        int ec = e < re ? e : re - 1;
        int sv = srcS[ec];
        const short* hbh = hhi + (long)sv * H;
        const short* hbl = hlo + (long)sv * H;
        short8 hh0 = *(const short8*)(hbh + 8 * q);
        short8 hh1 = *(const short8*)(hbh + 32 + 8 * q);
        short8 hl0 = *(const short8*)(hbl + 8 * q);
        short8 hl1 = *(const short8*)(hbl + 32 + 8 * q);

        floatx4 p4[4];
#pragma unroll
        for (int t = 0; t < 4; ++t) p4[t] = (floatx4){0.f, 0.f, 0.f, 0.f};
#pragma unroll
        for (int t = 0; t < 4; ++t) {
          p4[t] = MFMA(hh0, w1hiR[t][0], p4[t]);
          p4[t] = MFMA(hh1, w1hiR[t][1], p4[t]);
          p4[t] = MFMA(hl0, w1hiR[t][0], p4[t]);
          p4[t] = MFMA(hl1, w1hiR[t][1], p4[t]);
          p4[t] = MFMA(hh0, w1loR[t][0], p4[t]);
          p4[t] = MFMA(hh1, w1loR[t][1], p4[t]);
        }
        // relu + bias + tail-mask + accumulate (P[e=4q+r][f=16t+m])
#pragma unroll
        for (int r = 0; r < 4; ++r) {
          bool ok = (base + 4 * q + r) < re;
#pragma unroll
          for (int t = 0; t < 4; ++t) {
            float v = fmaxf(p4[t][r] + b1r[t], 0.f);
            sum[t][r] += ok ? v : 0.f;
          }
        }
      }
      // e-sum: in-lane over r, then across q
      float sf[4];
#pragma unroll
      for (int t = 0; t < 4; ++t) {
        float s = sum[t][0] + sum[t][1] + sum[t][2] + sum[t][3];
        s += __shfl_xor(s, 16);
        s += __shfl_xor(s, 32);
        sf[t] = s;
      }
      // deposit sumP[f=16q+m] (reg t==q) -> batch row b, slot=lane
      float sel = (q == 0) ? sf[0] : (q == 1) ? sf[1] : (q == 2) ? sf[2] : sf[3];
      bb_buf[b * BSTR + lane] = packhl(sel);
      if (lane == 0) degs[wave][b] = re - rs;
    }
    // ---- batch GEMM2: sumP(16x64) @ W2 ----
    short8 ahi[2], alo[2];
#pragma unroll
    for (int c = 0; c < 2; ++c)
      unpack8(&bb_buf[m * BSTR + 32 * c + 8 * q], ahi[c], alo[c]);

    floatx4 m4[4];
#pragma unroll
    for (int t = 0; t < 4; ++t) m4[t] = (floatx4){0.f, 0.f, 0.f, 0.f};
#pragma unroll
    for (int t = 0; t < 4; ++t) {
      short8 b0h, b0l, b1h, b1l;
      unpack8(&w2p[(((t * 2 + 0) * 64) + lane) * 8], b0h, b0l);
      unpack8(&w2p[(((t * 2 + 1) * 64) + lane) * 8], b1h, b1l);
      m4[t] = MFMA(ahi[0], b0h, m4[t]);
      m4[t] = MFMA(ahi[1], b1h, m4[t]);
      m4[t] = MFMA(alo[0], b0h, m4[t]);
      m4[t] = MFMA(alo[1], b1h, m4[t]);
      m4[t] = MFMA(ahi[0], b0l, m4[t]);
      m4[t] = MFMA(ahi[1], b1l, m4[t]);
    }
    // epilogue: agg[node=4q+r][col=16t+m] = M + deg*b2
#pragma unroll
    for (int r = 0; r < 4; ++r) {
      int nd = nb0 + 4 * q + r;
      if (nd < N) {
        float dv = (float)degs[wave][4 * q + r];
#pragma unroll
        for (int t = 0; t < 4; ++t) {
          int col = 16 * t + m;
          agg[(long)nd * H + col] = m4[t][r] + dv * b2s[col];
        }
      }
    }
  }
}

// per-node update MLP + BN + residual relu; h in hi/lo planes, in-place safe.
__global__ __launch_bounds__(256) void k_upd2(
    short* __restrict__ hhi, short* __restrict__ hlo, const float* __restrict__ agg,
    const void* __restrict__ W1, const void* __restrict__ B1,
    const void* __restrict__ W2, const void* __restrict__ B2,
    const void* __restrict__ G, const void* __restrict__ Bb,
    const void* __restrict__ Mm, const void* __restrict__ Vv,
    long oU, long oW, long oB, const int* __restrict__ flag, int N) {
  __shared__ short w1hi[64 * PADU], w1lo[64 * PADU];
  __shared__ short w2hi[64 * PADW], w2lo[64 * PADW];
  __shared__ float b1s[64], b2s[64], scl[64], sft[64];
  __shared__ float tbuf[4][16 * PADT];

  bool isf32 = (*flag != 0);
  int tid = threadIdx.x;
  for (int idx = tid; idx < 8192; idx += 256) {
    int j = idx >> 6, k = idx & 63;
    short hi, lo;
    split2(ldf(W1, oU + idx, isf32), hi, lo);
    w1hi[k * PADU + j] = hi; w1lo[k * PADU + j] = lo;
  }
  for (int idx = tid; idx < 4096; idx += 256) {
    int j = idx >> 6, k = idx & 63;
    short hi, lo;
    split2(ldf(W2, oW + idx, isf32), hi, lo);
    w2hi[k * PADW + j] = hi; w2lo[k * PADW + j] = lo;
  }
  if (tid < 64) {
    b1s[tid] = ldf(B1, oB + tid, isf32);
    b2s[tid] = ldf(B2, oB + tid, isf32);
    float s = ldf(G, oB + tid, isf32) * rsqrtf(ldf(Vv, oB + tid, isf32) + 1e-5f);
    scl[tid] = s;
    sft[tid] = ldf(Bb, oB + tid, isf32) - ldf(Mm, oB + tid, isf32) * s;
  }
  __syncthreads();

  const int wave = tid >> 6, lane = tid & 63;
  const int m = lane & 15, quad = lane >> 4;
  const int nBase = (blockIdx.x * 4 + wave) * 16;
  int node = nBase + m;
  int nc = node < N ? node : N - 1;

  short8 fhi[4], flo[4];
  fhi[0] = *(const short8*)(hhi + (long)nc * H + quad * 8);
  fhi[1] = *(const short8*)(hhi + (long)nc * H + 32 + quad * 8);
  flo[0] = *(const short8*)(hlo + (long)nc * H + quad * 8);
  flo[1] = *(const short8*)(hlo + (long)nc * H + 32 + quad * 8);
  {
    const float* arow = agg + (long)nc * H;
    float gv[16];
    *(floatx4*)(gv + 0)  = *(const floatx4*)(arow + quad * 8);
    *(floatx4*)(gv + 4)  = *(const floatx4*)(arow + quad * 8 + 4);
    *(floatx4*)(gv + 8)  = *(const floatx4*)(arow + 32 + quad * 8);
    *(floatx4*)(gv + 12) = *(const floatx4*)(arow + 32 + quad * 8 + 4);
#pragma unroll
    for (int j = 0; j < 8; ++j) {
      short hi, lo;
      split2(gv[j], hi, lo);      fhi[2][j] = hi; flo[2][j] = lo;
      split2(gv[8 + j], hi, lo);  fhi[3][j] = hi; flo[3][j] = lo;
    }
  }

  floatx4 acc[4];
#pragma unroll
  for (int t = 0; t < 4; ++t) acc[t] = (floatx4){0.f, 0.f, 0.f, 0.f};
#pragma unroll
  for (int t = 0; t < 4; ++t) {
    const short* whi = &w1hi[(t * 16 + m) * PADU + quad * 8];
    const short* wlo = &w1lo[(t * 16 + m) * PADU + quad * 8];
#pragma unroll
    for (int c = 0; c < 4; ++c) {
      acc[t] = MFMA(fhi[c], *(const short8*)(whi + 32 * c), acc[t]);
      acc[t] = MFMA(flo[c], *(const short8*)(whi + 32 * c), acc[t]);
      acc[t] = MFMA(fhi[c], *(const short8*)(wlo + 32 * c), acc[t]);
    }
  }

  float* tb = tbuf[wave];
#pragma unroll
  for (int t = 0; t < 4; ++t) {
    int col = t * 16 + m;
    float bb = b1s[col];
#pragma unroll
    for (int r = 0; r < 4; ++r)
      tb[(quad * 4 + r) * PADT + col] = fmaxf(acc[t][r] + bb, 0.f);
  }
  __syncthreads();

  float av[16];
  *(floatx4*)(av + 0)  = *(const floatx4*)(&tb[m * PADT + quad * 8]);
  *(floatx4*)(av + 4)  = *(const floatx4*)(&tb[m * PADT + quad * 8 + 4]);
  *(floatx4*)(av + 8)  = *(const floatx4*)(&tb[m * PADT + 32 + quad * 8]);
  *(floatx4*)(av + 12) = *(const floatx4*)(&tb[m * PADT + 32 + quad * 8 + 4]);
  short8 thi0, tlo0, thi1, tlo1;
#pragma unroll
  for (int j = 0; j < 8; ++j) {
    short hi, lo;
    split2(av[j], hi, lo);     thi0[j] = hi; tlo0[j] = lo;
    split2(av[8 + j], hi, lo); thi1[j] = hi; tlo1[j] = lo;
  }

  floatx4 mac[4];
#pragma unroll
  for (int t = 0; t < 4; ++t) mac[t] = (floatx4){0.f, 0.f, 0.f, 0.f};
#pragma unroll
  for (int t = 0; t < 4; ++t) {
    const short* whi = &w2hi[(t * 16 + m) * PADW + quad * 8];
    const short* wlo = &w2lo[(t * 16 + m) * PADW + quad * 8];
    mac[t] = MFMA(thi0, *(const short8*)(whi), mac[t]);
    mac[t] = MFMA(thi1, *(const short8*)(whi + 32), mac[t]);
    mac[t] = MFMA(tlo0, *(const short8*)(whi), mac[t]);
    mac[t] = MFMA(tlo1, *(const short8*)(whi + 32), mac[t]);
    mac[t] = MFMA(thi0, *(const short8*)(wlo), mac[t]);
    mac[t] = MFMA(thi1, *(const short8*)(wlo + 32), mac[t]);
  }

#pragma unroll
  for (int t = 0; t < 4; ++t) {
    int col = t * 16 + m;
    float bb = b2s[col], ss = scl[col], ff = sft[col];
#pragma unroll
    for (int r = 0; r < 4; ++r) {
      int nrow = nBase + quad * 4 + r;
      if (nrow < N) {
        long el = (long)nrow * H + col;
        float hv = (mac[t][r] + bb) * ss + ff;
        float ho = bf2f(hhi[el]) + bf2f(hlo[el]);
        float hn = fmaxf(hv + ho, 0.f);
        short hi, lo; split2(hn, hi, lo);
        hhi[el] = hi; hlo[el] = lo;
      }
    }
  }
}

// readout from hi/lo planes
__global__ __launch_bounds__(256) void k_out2(
    const short* __restrict__ hhi, const short* __restrict__ hlo,
    const void* __restrict__ W1, const void* __restrict__ B1,
    const void* __restrict__ W2, const void* __restrict__ B2,
    void* __restrict__ out, const int* __restrict__ flag, int NQ) {
  __shared__ float w1s[64 * 32];
  __shared__ float b1sh[32], w2s[32];
  bool isf32 = (*flag != 0);
  int tid = threadIdx.x;
  for (int idx = tid; idx < 2048; idx += 256) w1s[idx] = ldf(W1, idx, isf32);
  if (tid < 32) { b1sh[tid] = ldf(B1, tid, isf32); w2s[tid] = ldf(W2, tid, isf32); }
  __syncthreads();
  int v = blockIdx.x * 256 + tid;
  if (v >= NQ) return;
  float hr[64];
#pragma unroll
  for (int j = 0; j < 64; ++j)
    hr[j] = bf2f(hhi[(long)v * H + j]) + bf2f(hlo[(long)v * H + j]);
  float accum = ldf(B2, 0, isf32);
#pragma unroll 4
  for (int k = 0; k < 32; ++k) {
    float t = b1sh[k];
#pragma unroll
    for (int j = 0; j < 64; ++j) t += hr[j] * w1s[j * 32 + k];
    accum += fmaxf(t, 0.f) * w2s[k];
  }
  if (isf32) ((float*)out)[v] = accum;
  else ((short*)out)[v] = f2bf(accum);
}

// ---------------- old fallback path (round-3, f32 h) ----------------

__global__ void k_input(const void* __restrict__ x, const void* __restrict__ w,
                        const void* __restrict__ b, float* __restrict__ h,
                        const int* __restrict__ flag, int N) {
  bool isf32 = (*flag != 0);
  int idx = blockIdx.x * 256 + threadIdx.x;
  if (idx >= N * H) return;
  int v = idx >> 6, k = idx & 63;
  float acc = ldf(b, k, isf32);
#pragma unroll
  for (int d = 0; d < 3; ++d)
    acc += ldf(x, (long)v * 3 + d, isf32) * ldf(w, d * 64 + k, isf32);
  h[idx] = fmaxf(acc, 0.f);
}

template <bool AF32>
__global__ __launch_bounds__(256) void k_msg(
    const float* __restrict__ h, const int* __restrict__ srcI, const int* __restrict__ dstI,
    const void* __restrict__ W1, const void* __restrict__ B1,
    const void* __restrict__ W2, const void* __restrict__ B2,
    long oW, long oB,
    void* __restrict__ aggv, const int* __restrict__ flag, int E) {
  __shared__ short w1hi[64 * PADW], w1lo[64 * PADW];
  __shared__ short w2hi[64 * PADW], w2lo[64 * PADW];
  __shared__ float b1s[64], b2s[64];
  __shared__ float tbuf[4][16 * PADT];

  bool isf32 = (*flag != 0);
  int tid = threadIdx.x;
  for (int idx = tid; idx < 4096; idx += 256) {
    int j = idx >> 6, k = idx & 63;
    short hi, lo;
    split2(ldf(W1, oW + idx, isf32), hi, lo);
    w1hi[k * PADW + j] = hi; w1lo[k * PADW + j] = lo;
    split2(ldf(W2, oW + idx, isf32), hi, lo);
    w2hi[k * PADW + j] = hi; w2lo[k * PADW + j] = lo;
  }
  if (tid < 64) {
    b1s[tid] = ldf(B1, oB + tid, isf32);
    b2s[tid] = ldf(B2, oB + tid, isf32);
  }
  __syncthreads();

  const int wave = tid >> 6, lane = tid & 63;
  const int m = lane & 15, quad = lane >> 4;
  const int eBase = (blockIdx.x * 4 + wave) * 16;

  int e = eBase + m;
  int ec = e < E ? e : E - 1;
  int sv = srcI[ec];
  int dv = dstI[ec];

  const float* hrow = h + (long)sv * H;
  float av[16];
  *(floatx4*)(av + 0)  = *(const floatx4*)(hrow + quad * 8);
  *(floatx4*)(av + 4)  = *(const floatx4*)(hrow + quad * 8 + 4);
  *(floatx4*)(av + 8)  = *(const floatx4*)(hrow + 32 + quad * 8);
  *(floatx4*)(av + 12) = *(const floatx4*)(hrow + 32 + quad * 8 + 4);
  short8 ahi0, alo0, ahi1, alo1;
#pragma unroll
  for (int j = 0; j < 8; ++j) {
    short hi, lo;
    split2(av[j], hi, lo);     ahi0[j] = hi; alo0[j] = lo;
    split2(av[8 + j], hi, lo); ahi1[j] = hi; alo1[j] = lo;
  }

  floatx4 acc[4];
#pragma unroll
  for (int t = 0; t < 4; ++t) acc[t] = (floatx4){0.f, 0.f, 0.f, 0.f};
#pragma unroll
  for (int t = 0; t < 4; ++t) {
    const short* whi = &w1hi[(t * 16 + m) * PADW + quad * 8];
    const short* wlo = &w1lo[(t * 16 + m) * PADW + quad * 8];
    acc[t] = MFMA(ahi0, *(const short8*)(whi), acc[t]);
    acc[t] = MFMA(ahi1, *(const short8*)(whi + 32), acc[t]);
    acc[t] = MFMA(alo0, *(const short8*)(whi), acc[t]);
    acc[t] = MFMA(alo1, *(const short8*)(whi + 32), acc[t]);
    acc[t] = MFMA(ahi0, *(const short8*)(wlo), acc[t]);
    acc[t] = MFMA(ahi1, *(const short8*)(wlo + 32), acc[t]);
  }

  float* tb = tbuf[wave];
#pragma unroll
  for (int t = 0; t < 4; ++t) {
    int col = t * 16 + m;
    float bb = b1s[col];
#pragma unroll
    for (int r = 0; r < 4; ++r)
      tb[(quad * 4 + r) * PADT + col] = fmaxf(acc[t][r] + bb, 0.f);
  }
  __syncthreads();

  *(floatx4*)(av + 0)  = *(const floatx4*)(&tb[m * PADT + quad * 8]);
  *(floatx4*)(av + 4)  = *(const floatx4*)(&tb[m * PADT + quad * 8 + 4]);
  *(floatx4*)(av + 8)  = *(const floatx4*)(&tb[m * PADT + 32 + quad * 8]);
  *(floatx4*)(av + 12) = *(const floatx4*)(&tb[m * PADT + 32 + quad * 8 + 4]);
#pragma unroll
  for (int j = 0; j < 8; ++j) {
    short hi, lo;
    split2(av[j], hi, lo);     ahi0[j] = hi; alo0[j] = lo;
    split2(av[8 + j], hi, lo); ahi1[j] = hi; alo1[j] = lo;
  }

  floatx4 mac[4];
#pragma unroll
  for (int t = 0; t < 4; ++t) mac[t] = (floatx4){0.f, 0.f, 0.f, 0.f};
#pragma unroll
  for (int t = 0; t < 4; ++t) {
    const short* whi = &w2hi[(t * 16 + m) * PADW + quad * 8];
    const short* wlo = &w2lo[(t * 16 + m) * PADW + quad * 8];
    mac[t] = MFMA(ahi0, *(const short8*)(whi), mac[t]);
    mac[t] = MFMA(ahi1, *(const short8*)(whi + 32), mac[t]);
    mac[t] = MFMA(alo0, *(const short8*)(whi), mac[t]);
    mac[t] = MFMA(alo1, *(const short8*)(whi + 32), mac[t]);
    mac[t] = MFMA(ahi0, *(const short8*)(wlo), mac[t]);
    mac[t] = MFMA(ahi1, *(const short8*)(wlo + 32), mac[t]);
  }

  float* aggF = (float*)aggv;
  short* aggS = (short*)aggv;
#pragma unroll
  for (int t = 0; t < 4; ++t) {
    int col = t * 16 + m;
    float bb = b2s[col];
#pragma unroll
    for (int r = 0; r < 4; ++r) {
      int row = quad * 4 + r;
      int er = eBase + row;
      int dr = __shfl(dv, row);
      float v = mac[t][r] + bb;
      if (AF32) {
        if (er < E) atomicAdd(&aggF[(long)dr * H + col], v);
      } else {
        float v2 = __shfl_down(v, 1);
        if (((m & 1) == 0) && er < E) {
          unsigned int pk = ((unsigned int)(unsigned short)f2bf(v2) << 16) |
                            (unsigned int)(unsigned short)f2bf(v);
          unsafeAtomicAdd((__hip_bfloat162*)&aggS[(long)dr * H + col],
                          *(__hip_bfloat162*)&pk);
        }
      }
    }
  }
}

template <bool AF32>
__global__ __launch_bounds__(256) void k_upd(
    const float* __restrict__ h, const void* __restrict__ aggv,
    const void* __restrict__ W1, const void* __restrict__ B1,
    const void* __restrict__ W2, const void* __restrict__ B2,
    const void* __restrict__ G, const void* __restrict__ Bb,
    const void* __restrict__ Mm, const void* __restrict__ Vv,
    long oU, long oW, long oB,
    float* __restrict__ hout, const int* __restrict__ flag, int N) {
  __shared__ short w1hi[64 * PADU], w1lo[64 * PADU];
  __shared__ short w2hi[64 * PADW], w2lo[64 * PADW];
  __shared__ float b1s[64], b2s[64], scl[64], sft[64];
  __shared__ float tbuf[4][16 * PADT];

  bool isf32 = (*flag != 0);
  int tid = threadIdx.x;
  for (int idx = tid; idx < 8192; idx += 256) {
    int j = idx >> 6, k = idx & 63;
    short hi, lo;
    split2(ldf(W1, oU + idx, isf32), hi, lo);
    w1hi[k * PADU + j] = hi; w1lo[k * PADU + j] = lo;
  }
  for (int idx = tid; idx < 4096; idx += 256) {
    int j = idx >> 6, k = idx & 63;
    short hi, lo;
    split2(ldf(W2, oW + idx, isf32), hi, lo);
    w2hi[k * PADW + j] = hi; w2lo[k * PADW + j] = lo;
  }
  if (tid < 64) {
    b1s[tid] = ldf(B1, oB + tid, isf32);
    b2s[tid] = ldf(B2, oB + tid, isf32);
    float s = ldf(G, oB + tid, isf32) * rsqrtf(ldf(Vv, oB + tid, isf32) + 1e-5f);
    scl[tid] = s;
    sft[tid] = ldf(Bb, oB + tid, isf32) - ldf(Mm, oB + tid, isf32) * s;
  }
  __syncthreads();

  const int wave = tid >> 6, lane = tid & 63;
  const int m = lane & 15, quad = lane >> 4;
  const int nBase = (blockIdx.x * 4 + wave) * 16;
  int node = nBase + m;
  int nc = node < N ? node : N - 1;

  float av[16];
  const float* hrow = h + (long)nc * H;
  *(floatx4*)(av + 0)  = *(const floatx4*)(hrow + quad * 8);
  *(floatx4*)(av + 4)  = *(const floatx4*)(hrow + quad * 8 + 4);
  *(floatx4*)(av + 8)  = *(const floatx4*)(hrow + 32 + quad * 8);
  *(floatx4*)(av + 12) = *(const floatx4*)(hrow + 32 + quad * 8 + 4);
  float gv[16];
  if (AF32) {
    const float* arow = (const float*)aggv + (long)nc * H;
    *(floatx4*)(gv + 0)  = *(const floatx4*)(arow + quad * 8);
    *(floatx4*)(gv + 4)  = *(const floatx4*)(arow + quad * 8 + 4);
    *(floatx4*)(gv + 8)  = *(const floatx4*)(arow + 32 + quad * 8);
    *(floatx4*)(gv + 12) = *(const floatx4*)(arow + 32 + quad * 8 + 4);
  } else {
    const short* arow = (const short*)aggv + (long)nc * H;
#pragma unroll
    for (int j = 0; j < 8; ++j) {
      gv[j] = bf2f(arow[quad * 8 + j]);
      gv[8 + j] = bf2f(arow[32 + quad * 8 + j]);
    }
  }
  short8 fhi[4], flo[4];
#pragma unroll
  for (int j = 0; j < 8; ++j) {
    short hi, lo;
    split2(av[j], hi, lo);      fhi[0][j] = hi; flo[0][j] = lo;
    split2(av[8 + j], hi, lo);  fhi[1][j] = hi; flo[1][j] = lo;
    split2(gv[j], hi, lo);      fhi[2][j] = hi; flo[2][j] = lo;
    split2(gv[8 + j], hi, lo);  fhi[3][j] = hi; flo[3][j] = lo;
  }

  floatx4 acc[4];
#pragma unroll
  for (int t = 0; t < 4; ++t) acc[t] = (floatx4){0.f, 0.f, 0.f, 0.f};
#pragma unroll
  for (int t = 0; t < 4; ++t) {
    const short* whi = &w1hi[(t * 16 + m) * PADU + quad * 8];
    const short* wlo = &w1lo[(t * 16 + m) * PADU + quad * 8];
#pragma unroll
    for (int c = 0; c < 4; ++c) {
      acc[t] = MFMA(fhi[c], *(const short8*)(whi + 32 * c), acc[t]);
      acc[t] = MFMA(flo[c], *(const short8*)(whi + 32 * c), acc[t]);
      acc[t] = MFMA(fhi[c], *(const short8*)(wlo + 32 * c), acc[t]);
    }
  }

  float* tb = tbuf[wave];
#pragma unroll
  for (int t = 0; t < 4; ++t) {
    int col = t * 16 + m;
    float bb = b1s[col];
#pragma unroll
    for (int r = 0; r < 4; ++r)
      tb[(quad * 4 + r) * PADT + col] = fmaxf(acc[t][r] + bb, 0.f);
  }
  __syncthreads();

  *(floatx4*)(av + 0)  = *(const floatx4*)(&tb[m * PADT + quad * 8]);
  *(floatx4*)(av + 4)  = *(const floatx4*)(&tb[m * PADT + quad * 8 + 4]);
  *(floatx4*)(av + 8)  = *(const floatx4*)(&tb[m * PADT + 32 + quad * 8]);
  *(floatx4*)(av + 12) = *(const floatx4*)(&tb[m * PADT + 32 + quad * 8 + 4]);
  short8 thi0, tlo0, thi1, tlo1;
#pragma unroll
  for (int j = 0; j < 8; ++j) {
    short hi, lo;
    split2(av[j], hi, lo);     thi0[j] = hi; tlo0[j] = lo;
    split2(av[8 + j], hi, lo); thi1[j] = hi; tlo1[j] = lo;
  }

  floatx4 mac[4];
#pragma unroll
  for (int t = 0; t < 4; ++t) mac[t] = (floatx4){0.f, 0.f, 0.f, 0.f};
#pragma unroll
  for (int t = 0; t < 4; ++t) {
    const short* whi = &w2hi[(t * 16 + m) * PADW + quad * 8];
    const short* wlo = &w2lo[(t * 16 + m) * PADW + quad * 8];
    mac[t] = MFMA(thi0, *(const short8*)(whi), mac[t]);
    mac[t] = MFMA(thi1, *(const short8*)(whi + 32), mac[t]);
    mac[t] = MFMA(tlo0, *(const short8*)(whi), mac[t]);
    mac[t] = MFMA(tlo1, *(const short8*)(whi + 32), mac[t]);
    mac[t] = MFMA(thi0, *(const short8*)(wlo), mac[t]);
    mac[t] = MFMA(thi1, *(const short8*)(wlo + 32), mac[t]);
  }

#pragma unroll
  for (int t = 0; t < 4; ++t) {
    int col = t * 16 + m;
    float bb = b2s[col], ss = scl[col], ff = sft[col];
#pragma unroll
    for (int r = 0; r < 4; ++r) {
      int nrow = nBase + quad * 4 + r;
      if (nrow < N) {
        float hv = (mac[t][r] + bb) * ss + ff;
        float ho = h[(long)nrow * H + col];
        hout[(long)nrow * H + col] = fmaxf(hv + ho, 0.f);
      }
    }
  }
}

__global__ __launch_bounds__(256) void k_out(
    const float* __restrict__ h, const void* __restrict__ W1, const void* __restrict__ B1,
    const void* __restrict__ W2, const void* __restrict__ B2,
    void* __restrict__ out, const int* __restrict__ flag, int NQ) {
  __shared__ float w1s[64 * 32];
  __shared__ float b1sh[32], w2s[32];
  bool isf32 = (*flag != 0);
  int tid = threadIdx.x;
  for (int idx = tid; idx < 2048; idx += 256) w1s[idx] = ldf(W1, idx, isf32);
  if (tid < 32) { b1sh[tid] = ldf(B1, tid, isf32); w2s[tid] = ldf(W2, tid, isf32); }
  __syncthreads();
  int v = blockIdx.x * 256 + tid;
  if (v >= NQ) return;
  float hr[64];
  const float* hp = h + (long)v * H;
#pragma unroll
  for (int j = 0; j < 64; ++j) hr[j] = hp[j];
  float accum = ldf(B2, 0, isf32);
#pragma unroll 4
  for (int k = 0; k < 32; ++k) {
    float t = b1sh[k];
#pragma unroll
    for (int j = 0; j < 64; ++j) t += hr[j] * w1s[j * 32 + k];
    accum += fmaxf(t, 0.f) * w2s[k];
  }
  if (isf32) ((float*)out)[v] = accum;
  else ((short*)out)[v] = f2bf(accum);
}

extern "C" void kernel_launch(void* const* d_in, const int* in_sizes, int n_in,
                              void* d_out, int out_size, void* d_ws, size_t ws_size,
                              hipStream_t stream) {
  const void* x      = d_in[0];
  const int*  ei     = (const int*)d_in[1];
  const void* w_in   = d_in[3];
  const void* b_in   = d_in[4];
  const void* msg_w1 = d_in[5];
  const void* msg_b1 = d_in[6];
  const void* msg_w2 = d_in[7];
  const void* msg_b2 = d_in[8];
  const void* upd_w1 = d_in[9];
  const void* upd_b1 = d_in[10];
  const void* upd_w2 = d_in[11];
  const void* upd_b2 = d_in[12];
  const void* bn_g   = d_in[13];
  const void* bn_b   = d_in[14];
  const void* bn_m   = d_in[15];
  const void* bn_v   = d_in[16];
  const void* out_w1 = d_in[17];
  const void* out_b1 = d_in[18];
  const void* out_w2 = d_in[19];
  const void* out_b2 = d_in[20];

  const int N = in_sizes[0] / 3;
  const int E = in_sizes[1] / 2;
  const int L = in_sizes[5] / (H * H);
  const int* srcI = ei;
  const int* dstI = ei + E;

  // workspace layout (256B-aligned slots)
  size_t off = 0;
  auto alloc = [&](size_t bytes) { size_t o = off; off += (bytes + 255) & ~(size_t)255; return o; };
  size_t o_flag   = alloc(256);
  size_t o_hhi    = alloc((size_t)N * H * sizeof(short));
  size_t o_hlo    = alloc((size_t)N * H * sizeof(short));
  size_t o_agg    = alloc((size_t)N * H * sizeof(float));
  size_t o_rowptr = alloc((size_t)(N + 1) * sizeof(int));
  size_t o_cursor = alloc((size_t)N * sizeof(int));
  size_t o_bsum   = alloc(256 * sizeof(int));
  size_t o_bexcl  = alloc(256 * sizeof(int));
  size_t o_srcS   = alloc((size_t)E * sizeof(int));
  const size_t needNew = off;
  const int NB = (N + 1023) >> 10;
  const bool newPath = (ws_size >= needNew) && (NB <= 256);

  char* ws = (char*)d_ws;
  int*   flag   = (int*)(ws + o_flag);
  short* hhi    = (short*)(ws + o_hhi);
  short* hlo    = (short*)(ws + o_hlo);
  float* agg    = (float*)(ws + o_agg);
  int*   rowptr = (int*)(ws + o_rowptr);
  int*   deg    = (int*)(ws + o_cursor);
  int*   bsum   = (int*)(ws + o_bsum);
  int*   bexcl  = (int*)(ws + o_bexcl);
  int*   srcS   = (int*)(ws + o_srcS);

  k_probe<<<1, 256, 0, stream>>>((const short*)x, flag);

  if (newPath) {
    k_input2<<<(N * H + 255) / 256, 256, 0, stream>>>(x, w_in, b_in, hhi, hlo, flag, N);

    hipMemsetAsync(deg, 0, (size_t)N * sizeof(int), stream);
    k_hist<<<(E + 255) / 256, 256, 0, stream>>>(dstI, deg, E);
    k_scan_local<<<NB, 256, 0, stream>>>(deg, rowptr, bsum, N);
    k_scan_block<<<1, 256, 0, stream>>>(bsum, bexcl, NB);
    k_scan_add<<<(N + 256) / 256, 256, 0, stream>>>(rowptr, deg, bexcl, N, E);
    k_scatter<<<(E + 255) / 256, 256, 0, stream>>>(srcI, dstI, deg, srcS, E);

    const int MSG_BLOCKS = 768;  // ~3 blocks/CU persistent
    for (int i = 0; i < L; ++i) {
      long oW = (long)i * H * H, oU = (long)i * 2 * H * H, oB = (long)i * H;
      k_msg2<<<MSG_BLOCKS, 256, 0, stream>>>(hhi, hlo, rowptr, srcS,
          msg_w1, msg_b1, msg_w2, msg_b2, oW, oB, agg, flag, N, MSG_BLOCKS * 4);
      k_upd2<<<(N + 63) / 64, 256, 0, stream>>>(hhi, hlo, agg,
          upd_w1, upd_b1, upd_w2, upd_b2, bn_g, bn_b, bn_m, bn_v,
          oU, oW, oB, flag, N);
    }
    k_out2<<<(out_size + 255) / 256, 256, 0, stream>>>(hhi, hlo,
        out_w1, out_b1, out_w2, out_b2, d_out, flag, out_size);
  } else {
    // fallback: round-3 atomic path with f32 h
    const size_t hBytes   = (size_t)N * H * sizeof(float);
    const size_t aggF32B  = (size_t)N * H * sizeof(float);
    const size_t aggBf16B = (size_t)N * H * sizeof(short);
    float* hA2 = (float*)(ws + 256);
    void* agg2 = (void*)((char*)hA2 + hBytes);
    const bool af32 = (ws_size >= 256 + hBytes + aggF32B);
    const size_t aggBytes = af32 ? aggF32B : aggBf16B;
    k_input<<<(N * H + 255) / 256, 256, 0, stream>>>(x, w_in, b_in, hA2, flag, N);
    for (int i = 0; i < L; ++i) {
      long oW = (long)i * H * H, oU = (long)i * 2 * H * H, oB = (long)i * H;
      hipMemsetAsync(agg2, 0, aggBytes, stream);
      if (af32) {
        k_msg<true><<<(E + 63) / 64, 256, 0, stream>>>(hA2, srcI, dstI,
            msg_w1, msg_b1, msg_w2, msg_b2, oW, oB, agg2, flag, E);
        k_upd<true><<<(N + 63) / 64, 256, 0, stream>>>(hA2, agg2,
            upd_w1, upd_b1, upd_w2, upd_b2, bn_g, bn_b, bn_m, bn_v,
            oU, oW, oB, hA2, flag, N);
      } else {
        k_msg<false><<<(E + 63) / 64, 256, 0, stream>>>(hA2, srcI, dstI,
            msg_w1, msg_b1, msg_w2, msg_b2, oW, oB, agg2, flag, E);
        k_upd<false><<<(N + 63) / 64, 256, 0, stream>>>(hA2, agg2,
            upd_w1, upd_b1, upd_w2, upd_b2, bn_g, bn_b, bn_m, bn_v,
            oU, oW, oB, hA2, flag, N);
      }
    }
    k_out<<<(out_size + 255) / 256, 256, 0, stream>>>(hA2,
        out_w1, out_b1, out_w2, out_b2, d_out, flag, out_size);
  }
}